// Round 5
// baseline (294.915 us; speedup 1.0000x reference)
//
#include <hip/hip_runtime.h>
#include <hip/hip_bf16.h>

#define BATCH 8
#define NN 2048
#define FI 256
#define FO 256
#define ALPHA 0.2f
#define NEG_BIG -9000000000000000.0f

typedef short bf16x8 __attribute__((ext_vector_type(8)));
typedef float floatx4 __attribute__((ext_vector_type(4)));

static __device__ __forceinline__ unsigned short f2bf(float f) {
  return __builtin_bit_cast(unsigned short, __float2bfloat16(f));
}
static __device__ __forceinline__ float bf2f(unsigned short u) {
  unsigned int x = ((unsigned int)u) << 16;
  return __builtin_bit_cast(float, x);
}

// ---------------- K0: prep — WT (bf16, [o][f]) + wa1/wa2 = W@a halves -------
__global__ __launch_bounds__(256) void prep_kernel(
    const float* __restrict__ W, const float* __restrict__ a,
    unsigned short* __restrict__ WT, float* __restrict__ wa1, float* __restrict__ wa2) {
  const int t = threadIdx.x;
  const int blk = blockIdx.x;
  if (blk < 64) {
    __shared__ float xt[32][33];
    const int tr = blk >> 3, tc = blk & 7;        // f-tile, o-tile
    const int r = t >> 3, o4 = t & 7;
    const float4 v = *(const float4*)(W + (size_t)(tr*32 + r)*FO + tc*32 + o4*4);
    xt[o4*4+0][r] = v.x; xt[o4*4+1][r] = v.y; xt[o4*4+2][r] = v.z; xt[o4*4+3][r] = v.w;
    __syncthreads();
    const int ol = t >> 3, f4 = t & 7;
    unsigned short u4[4];
    #pragma unroll
    for (int u = 0; u < 4; ++u) u4[u] = f2bf(xt[ol][f4*4 + u]);
    *(uint2*)(WT + (size_t)(tc*32 + ol)*FI + tr*32 + f4*4) = *(const uint2*)u4;
  } else {
    const int bk = blk - 64;
    const int f = bk*32 + (t >> 3), oc = t & 7;
    const float4* wrow = (const float4*)(W + (size_t)f*FO) + oc*8;
    const float4* a1v  = (const float4*)a + oc*8;
    const float4* a2v  = (const float4*)(a + FO) + oc*8;
    float p1 = 0.f, p2 = 0.f;
    #pragma unroll
    for (int i = 0; i < 8; ++i) {
      const float4 w = wrow[i], b1 = a1v[i], b2 = a2v[i];
      p1 += w.x*b1.x + w.y*b1.y + w.z*b1.z + w.w*b1.w;
      p2 += w.x*b2.x + w.y*b2.y + w.z*b2.z + w.w*b2.w;
    }
    p1 += __shfl_xor(p1, 1); p2 += __shfl_xor(p2, 1);
    p1 += __shfl_xor(p1, 2); p2 += __shfl_xor(p2, 2);
    p1 += __shfl_xor(p1, 4); p2 += __shfl_xor(p2, 4);
    if (oc == 0) { wa1[f] = p1; wa2[f] = p2; }
  }
}

// ---------------- K1: hT = (x@W)^T via bf16 MFMA, fused s1+s2, x read ONCE --
// grid (nt=32, b=8); tile 64n x 256o, BK=64. Wave wv owns o-strip [wv*64, +64).
__global__ __launch_bounds__(256) void hgemm_kernel(
    const float* __restrict__ x, const unsigned short* __restrict__ WT,
    const float* __restrict__ wa1, const float* __restrict__ wa2,
    unsigned short* __restrict__ hbT, float* __restrict__ s1, float* __restrict__ s2) {
  const int t = threadIdx.x;
  const int nt = blockIdx.x, b = blockIdx.y;
  const int n0 = nt*64;
  __shared__ __align__(16) unsigned short xs[64][72];
  __shared__ __align__(16) unsigned short ws[256][72];
  __shared__ float was1[256], was2[256];
  was1[t] = wa1[t];
  was2[t] = wa2[t];
  const int lane = t & 63, wv = t >> 6;
  const int wc = wv*64;
  const int ln = lane & 15, q8 = (lane >> 4)*8;
  const int srow = t >> 2, fq = (t & 3)*16;
  floatx4 acc[4][4];
  #pragma unroll
  for (int mb = 0; mb < 4; ++mb)
    #pragma unroll
    for (int nb = 0; nb < 4; ++nb) acc[mb][nb] = (floatx4){0.f,0.f,0.f,0.f};
  float sp1 = 0.f, sp2 = 0.f;
  for (int kt = 0; kt < 4; ++kt) {
    const int f0 = kt*64;
    #pragma unroll
    for (int p = 0; p < 4; ++p) {          // stage x 64n x 64f fp32 -> bf16
      const int idx = p*256 + t;
      const int row = idx >> 4, c4 = idx & 15;
      const float4 v = *(const float4*)(x + (size_t)(b*NN + n0 + row)*FI + f0 + c4*4);
      unsigned short u4[4] = {f2bf(v.x), f2bf(v.y), f2bf(v.z), f2bf(v.w)};
      *(uint2*)&xs[row][c4*4] = *(const uint2*)u4;
    }
    #pragma unroll
    for (int p = 0; p < 8; ++p) {          // stage WT 256o x 64f (uint4 = 8 shorts)
      const int idx = p*256 + t;
      const int o = idx >> 3, f8 = idx & 7;
      *(uint4*)&ws[o][f8*8] = *(const uint4*)(WT + (size_t)o*FI + f0 + f8*8);
    }
    __syncthreads();
    {                                      // s1,s2 partials: 16 f per thread
      const bf16x8 h0 = *(const bf16x8*)&xs[srow][fq];
      const bf16x8 h1 = *(const bf16x8*)&xs[srow][fq + 8];
      #pragma unroll
      for (int u = 0; u < 8; ++u) {
        const float hv0 = bf2f((unsigned short)h0[u]);
        const float hv1 = bf2f((unsigned short)h1[u]);
        sp1 = fmaf(hv0, was1[f0 + fq + u], sp1);
        sp1 = fmaf(hv1, was1[f0 + fq + 8 + u], sp1);
        sp2 = fmaf(hv0, was2[f0 + fq + u], sp2);
        sp2 = fmaf(hv1, was2[f0 + fq + 8 + u], sp2);
      }
    }
    #pragma unroll
    for (int ks = 0; ks < 2; ++ks) {
      bf16x8 af[4], bfr[4];
      #pragma unroll
      for (int mb = 0; mb < 4; ++mb)
        af[mb] = *(const bf16x8*)&xs[mb*16 + ln][ks*32 + q8];
      #pragma unroll
      for (int nb = 0; nb < 4; ++nb)
        bfr[nb] = *(const bf16x8*)&ws[wc + nb*16 + ln][ks*32 + q8];
      #pragma unroll
      for (int mb = 0; mb < 4; ++mb)
        #pragma unroll
        for (int nb = 0; nb < 4; ++nb)
          acc[mb][nb] = __builtin_amdgcn_mfma_f32_16x16x32_bf16(
              af[mb], bfr[nb], acc[mb][nb], 0, 0, 0);
    }
    __syncthreads();
  }
  sp1 += __shfl_xor(sp1, 1); sp2 += __shfl_xor(sp2, 1);
  sp1 += __shfl_xor(sp1, 2); sp2 += __shfl_xor(sp2, 2);
  if ((t & 3) == 0) {
    s1[b*NN + n0 + srow] = sp1;
    s2[b*NN + n0 + srow] = sp2;
  }
  const int quad = lane >> 4;
  #pragma unroll
  for (int mb = 0; mb < 4; ++mb)
    #pragma unroll
    for (int nb = 0; nb < 4; ++nb) {
      unsigned short u4[4];
      #pragma unroll
      for (int r = 0; r < 4; ++r) u4[r] = f2bf(acc[mb][nb][r]);
      const int o_loc = wc + nb*16 + ln;
      const int n_loc = mb*16 + quad*4;
      *(uint2*)(hbT + (size_t)(b*FO + o_loc)*NN + n0 + n_loc) = *(const uint2*)u4;
    }
}

// ---------------- K2: adj -> mask32 + column softmax partials (one pass) -----
__global__ __launch_bounds__(256) void adjstats_kernel(
    const int* __restrict__ adj, const float* __restrict__ s1, const float* __restrict__ s2,
    unsigned int* __restrict__ mask32, float* __restrict__ pm, float* __restrict__ pl) {
  const int t = threadIdx.x;
  const int jt = blockIdx.x, ic = blockIdx.y, b = blockIdx.z;
  const int i0 = ic*256;
  __shared__ unsigned short bitsm[16][260];   // [j16][i], pad 260 vs 256
  __shared__ float s1s[256];
  s1s[t] = s1[b*NN + i0 + t];
  const int rr = t >> 4, j16 = t & 15;
  #pragma unroll 4
  for (int p = 0; p < 16; ++p) {
    const int row = p*16 + rr;
    const int4* src = (const int4*)(adj + (size_t)(b*NN + i0 + row)*NN + jt*256 + j16*16);
    const int4 q0 = src[0], q1 = src[1], q2 = src[2], q3 = src[3];
    unsigned int m = 0;
    m |= (unsigned int)(q0.x != 0) << 0;  m |= (unsigned int)(q0.y != 0) << 1;
    m |= (unsigned int)(q0.z != 0) << 2;  m |= (unsigned int)(q0.w != 0) << 3;
    m |= (unsigned int)(q1.x != 0) << 4;  m |= (unsigned int)(q1.y != 0) << 5;
    m |= (unsigned int)(q1.z != 0) << 6;  m |= (unsigned int)(q1.w != 0) << 7;
    m |= (unsigned int)(q2.x != 0) << 8;  m |= (unsigned int)(q2.y != 0) << 9;
    m |= (unsigned int)(q2.z != 0) << 10; m |= (unsigned int)(q2.w != 0) << 11;
    m |= (unsigned int)(q3.x != 0) << 12; m |= (unsigned int)(q3.y != 0) << 13;
    m |= (unsigned int)(q3.z != 0) << 14; m |= (unsigned int)(q3.w != 0) << 15;
    bitsm[j16][row] = (unsigned short)m;
  }
  __syncthreads();
  #pragma unroll
  for (int p = 0; p < 8; ++p) {               // coalesced mask32 write
    const int idx = p*256 + t;
    const int il = idx >> 3, wl = idx & 7;
    const unsigned int d = (unsigned int)bitsm[2*wl][il]
                         | ((unsigned int)bitsm[2*wl + 1][il] << 16);
    mask32[(size_t)(b*NN + i0 + il)*64 + jt*8 + wl] = d;
  }
  const int j = jt*256 + t;
  const float s2j = s2[b*NN + j];
  const int c16 = t >> 4, sh = t & 15;
  float M0 = NEG_BIG, M1 = NEG_BIG, M2 = NEG_BIG, M3 = NEG_BIG;
  for (int i = 0; i < 256; i += 4) {
    const uint2 w = *(const uint2*)&bitsm[c16][i];
    M0 = fmaxf(M0, ((w.x >> sh) & 1u)        ? s1s[i+0] : NEG_BIG);
    M1 = fmaxf(M1, ((w.x >> (16+sh)) & 1u)   ? s1s[i+1] : NEG_BIG);
    M2 = fmaxf(M2, ((w.y >> sh) & 1u)        ? s1s[i+2] : NEG_BIG);
    M3 = fmaxf(M3, ((w.y >> (16+sh)) & 1u)   ? s1s[i+3] : NEG_BIG);
  }
  const float M = fmaxf(fmaxf(M0, M1), fmaxf(M2, M3));
  float m;
  if (M == NEG_BIG) m = NEG_BIG;
  else { const float e = M + s2j; m = fmaxf(e, ALPHA*e); }
  float l0 = 0.f, l1 = 0.f, l2 = 0.f, l3 = 0.f;
  for (int i = 0; i < 256; i += 4) {
    const uint2 w = *(const uint2*)&bitsm[c16][i];
    float e0 = s1s[i+0] + s2j; e0 = fmaxf(e0, ALPHA*e0);
    float e1 = s1s[i+1] + s2j; e1 = fmaxf(e1, ALPHA*e1);
    float e2 = s1s[i+2] + s2j; e2 = fmaxf(e2, ALPHA*e2);
    float e3 = s1s[i+3] + s2j; e3 = fmaxf(e3, ALPHA*e3);
    l0 += __expf((((w.x >> sh) & 1u)      ? e0 : NEG_BIG) - m);
    l1 += __expf((((w.x >> (16+sh)) & 1u) ? e1 : NEG_BIG) - m);
    l2 += __expf((((w.y >> sh) & 1u)      ? e2 : NEG_BIG) - m);
    l3 += __expf((((w.y >> (16+sh)) & 1u) ? e3 : NEG_BIG) - m);
  }
  pm[(ic*BATCH + b)*NN + j] = m;
  pl[(ic*BATCH + b)*NN + j] = (l0 + l1) + (l2 + l3);
}

// ---------------- K3: out = elu(P @ h), P on the fly; combine folded in -----
// grid (it=32, ot=2, b=8): consecutive blocks share the V-slice (L2 locality).
__global__ __launch_bounds__(256) void agg_kernel(
    const unsigned int* __restrict__ mask32, const float* __restrict__ s1,
    const float* __restrict__ s2, const float* __restrict__ pm, const float* __restrict__ pl,
    const unsigned short* __restrict__ hbT, float* __restrict__ out) {
  const int t = threadIdx.x;
  const int it = blockIdx.x, ot = blockIdx.y, b = blockIdx.z;
  __shared__ __align__(16) unsigned short Pt[64*40];
  __shared__ __align__(16) unsigned short Vt[128*40];
  __shared__ float s2s[NN];
  __shared__ float mpls[NN];
  #pragma unroll
  for (int q = 0; q < 8; ++q) {               // combine: mpl = m + log l
    const int j = q*256 + t;
    float m = NEG_BIG;
    #pragma unroll
    for (int c = 0; c < 8; ++c) m = fmaxf(m, pm[(c*BATCH + b)*NN + j]);
    float l = 0.f;
    #pragma unroll
    for (int c = 0; c < 8; ++c)
      l += pl[(c*BATCH + b)*NN + j] * __expf(pm[(c*BATCH + b)*NN + j] - m);
    mpls[j] = m + __logf(l);
    s2s[j] = s2[b*NN + j];
  }
  const int prow = t >> 2;
  const int kq = (t & 3) * 8;
  const int i = it*64 + prow;
  const float s1i = s1[b*NN + i];
  const unsigned int* m32row = mask32 + (size_t)(b*NN + i)*64;
  const unsigned short* vsrc0 = hbT + (size_t)(b*FO + ot*128 + prow)*NN;
  const unsigned short* vsrc1 = hbT + (size_t)(b*FO + ot*128 + prow + 64)*NN;
  const int lane = t & 63, wv = t >> 6;
  const int wr = (wv & 1)*32;
  const int wc = (wv >> 1)*64;
  const int ln = lane & 15, q8 = (lane >> 4)*8;
  floatx4 acc[2][4];
  #pragma unroll
  for (int mb = 0; mb < 2; ++mb)
    #pragma unroll
    for (int nb = 0; nb < 4; ++nb) acc[mb][nb] = (floatx4){0.f,0.f,0.f,0.f};
  __syncthreads();
  for (int kt = 0; kt < NN/32; ++kt) {
    const int j0 = kt*32;
    const unsigned int bits = m32row[kt] >> kq;
    __align__(16) unsigned short pv[8];
    #pragma unroll
    for (int kk = 0; kk < 8; ++kk) {
      const int k = j0 + kq + kk;
      float e = s1i + s2s[k];
      e = fmaxf(e, ALPHA*e);
      const float vvv = ((bits >> kk) & 1u) ? e : NEG_BIG;
      pv[kk] = f2bf(__expf(vvv - mpls[k]));
    }
    *(uint4*)&Pt[prow*40 + kq] = *(const uint4*)pv;
    *(uint4*)&Vt[prow*40 + kq]      = *(const uint4*)(vsrc0 + j0 + kq);
    *(uint4*)&Vt[(prow+64)*40 + kq] = *(const uint4*)(vsrc1 + j0 + kq);
    __syncthreads();
    bf16x8 af[2], bfr[4];
    #pragma unroll
    for (int mb = 0; mb < 2; ++mb)
      af[mb] = *(const bf16x8*)&Pt[(wr + mb*16 + ln)*40 + q8];
    #pragma unroll
    for (int nb = 0; nb < 4; ++nb)
      bfr[nb] = *(const bf16x8*)&Vt[(wc + nb*16 + ln)*40 + q8];
    #pragma unroll
    for (int mb = 0; mb < 2; ++mb)
      #pragma unroll
      for (int nb = 0; nb < 4; ++nb)
        acc[mb][nb] = __builtin_amdgcn_mfma_f32_16x16x32_bf16(
            af[mb], bfr[nb], acc[mb][nb], 0, 0, 0);
    __syncthreads();
  }
  const int orow_base = it*64 + wr;
  const int ocol_base = ot*128 + wc;
  #pragma unroll
  for (int mb = 0; mb < 2; ++mb)
    #pragma unroll
    for (int nb = 0; nb < 4; ++nb)
      #pragma unroll
      for (int r = 0; r < 4; ++r) {
        float vvv = acc[mb][nb][r];
        vvv = vvv > 0.f ? vvv : (__expf(vvv) - 1.f);
        const int m_loc = orow_base + mb*16 + (lane >> 4)*4 + r;
        const int n_loc = ocol_base + nb*16 + ln;
        out[(size_t)(b*NN + m_loc)*FO + n_loc] = vvv;
      }
}

extern "C" void kernel_launch(void* const* d_in, const int* in_sizes, int n_in,
                              void* d_out, int out_size, void* d_ws, size_t ws_size,
                              hipStream_t stream) {
  const float* x  = (const float*)d_in[0];
  const int* adj  = (const int*)d_in[1];
  const float* W  = (const float*)d_in[2];
  const float* a  = (const float*)d_in[3];
  float* out = (float*)d_out;

  char* ws = (char*)d_ws;
  size_t off = 0;
  auto alloc = [&](size_t bytes) -> void* {
    void* p = ws + off; off += (bytes + 255) & ~(size_t)255; return p;
  };
  unsigned short* WT   = (unsigned short*)alloc((size_t)FI*FO*2);            // 128 KB
  float* wa1           = (float*)alloc(FO*4);
  float* wa2           = (float*)alloc(FO*4);
  unsigned short* hbT  = (unsigned short*)alloc((size_t)BATCH*FO*NN*2);      // 8 MB
  float* s1            = (float*)alloc((size_t)BATCH*NN*4);
  float* s2            = (float*)alloc((size_t)BATCH*NN*4);
  float* pm            = (float*)alloc((size_t)8*BATCH*NN*4);
  float* pl            = (float*)alloc((size_t)8*BATCH*NN*4);
  unsigned int* mask32 = (unsigned int*)alloc((size_t)BATCH*NN*(NN/32)*4);   // 4 MB

  prep_kernel<<<dim3(72), dim3(256), 0, stream>>>(W, a, WT, wa1, wa2);
  hgemm_kernel<<<dim3(32, BATCH), dim3(256), 0, stream>>>(x, WT, wa1, wa2, hbT, s1, s2);
  adjstats_kernel<<<dim3(8, 8, BATCH), dim3(256), 0, stream>>>(adj, s1, s2, mask32, pm, pl);
  agg_kernel<<<dim3(32, 2, BATCH), dim3(256), 0, stream>>>(mask32, s1, s2, pm, pl, hbT, out);
}

// Round 7
// 293.687 us; speedup vs baseline: 1.0042x; 1.0042x over previous
//
#include <hip/hip_runtime.h>
#include <hip/hip_bf16.h>

#define BATCH 8
#define NN 2048
#define FI 256
#define FO 256
#define ALPHA 0.2f
#define NEG_BIG -9000000000000000.0f

typedef short bf16x8 __attribute__((ext_vector_type(8)));
typedef float floatx4 __attribute__((ext_vector_type(4)));

static __device__ __forceinline__ unsigned short f2bf(float f) {
  return __builtin_bit_cast(unsigned short, __float2bfloat16(f));
}
static __device__ __forceinline__ float bf2f(unsigned short u) {
  unsigned int x = ((unsigned int)u) << 16;
  return __builtin_bit_cast(float, x);
}

// ---------------- K0: prep — WT (bf16, [o][f]) + wa1/wa2 = W@a halves -------
__global__ __launch_bounds__(256) void prep_kernel(
    const float* __restrict__ W, const float* __restrict__ a,
    unsigned short* __restrict__ WT, float* __restrict__ wa1, float* __restrict__ wa2) {
  const int t = threadIdx.x;
  const int blk = blockIdx.x;
  if (blk < 64) {
    __shared__ float xt[32][33];
    const int tr = blk >> 3, tc = blk & 7;        // f-tile, o-tile
    const int r = t >> 3, o4 = t & 7;
    const float4 v = *(const float4*)(W + (size_t)(tr*32 + r)*FO + tc*32 + o4*4);
    xt[o4*4+0][r] = v.x; xt[o4*4+1][r] = v.y; xt[o4*4+2][r] = v.z; xt[o4*4+3][r] = v.w;
    __syncthreads();
    const int ol = t >> 3, f4 = t & 7;
    unsigned short u4[4];
    #pragma unroll
    for (int u = 0; u < 4; ++u) u4[u] = f2bf(xt[ol][f4*4 + u]);
    *(uint2*)(WT + (size_t)(tc*32 + ol)*FI + tr*32 + f4*4) = *(const uint2*)u4;
  } else {
    const int bk = blk - 64;
    const int f = bk*32 + (t >> 3), oc = t & 7;
    const float4* wrow = (const float4*)(W + (size_t)f*FO) + oc*8;
    const float4* a1v  = (const float4*)a + oc*8;
    const float4* a2v  = (const float4*)(a + FO) + oc*8;
    float p1 = 0.f, p2 = 0.f;
    #pragma unroll
    for (int i = 0; i < 8; ++i) {
      const float4 w = wrow[i], b1 = a1v[i], b2 = a2v[i];
      p1 += w.x*b1.x + w.y*b1.y + w.z*b1.z + w.w*b1.w;
      p2 += w.x*b2.x + w.y*b2.y + w.z*b2.z + w.w*b2.w;
    }
    p1 += __shfl_xor(p1, 1); p2 += __shfl_xor(p2, 1);
    p1 += __shfl_xor(p1, 2); p2 += __shfl_xor(p2, 2);
    p1 += __shfl_xor(p1, 4); p2 += __shfl_xor(p2, 4);
    if (oc == 0) { wa1[f] = p1; wa2[f] = p2; }
  }
}

// ---------------- K1: hT = (x@W)^T via bf16 MFMA, fused s1+s2, x read ONCE --
__global__ __launch_bounds__(256) void hgemm_kernel(
    const float* __restrict__ x, const unsigned short* __restrict__ WT,
    const float* __restrict__ wa1, const float* __restrict__ wa2,
    unsigned short* __restrict__ hbT, float* __restrict__ s1, float* __restrict__ s2) {
  const int t = threadIdx.x;
  const int nt = blockIdx.x, b = blockIdx.y;
  const int n0 = nt*64;
  __shared__ __align__(16) unsigned short xs[64][72];
  __shared__ __align__(16) unsigned short ws[256][72];
  __shared__ float was1[256], was2[256];
  was1[t] = wa1[t];
  was2[t] = wa2[t];
  const int lane = t & 63, wv = t >> 6;
  const int wc = wv*64;
  const int ln = lane & 15, q8 = (lane >> 4)*8;
  const int srow = t >> 2, fq = (t & 3)*16;
  floatx4 acc[4][4];
  #pragma unroll
  for (int mb = 0; mb < 4; ++mb)
    #pragma unroll
    for (int nb = 0; nb < 4; ++nb) acc[mb][nb] = (floatx4){0.f,0.f,0.f,0.f};
  float sp1 = 0.f, sp2 = 0.f;
  for (int kt = 0; kt < 4; ++kt) {
    const int f0 = kt*64;
    #pragma unroll
    for (int p = 0; p < 4; ++p) {          // stage x 64n x 64f fp32 -> bf16
      const int idx = p*256 + t;
      const int row = idx >> 4, c4 = idx & 15;
      const float4 v = *(const float4*)(x + (size_t)(b*NN + n0 + row)*FI + f0 + c4*4);
      unsigned short u4[4] = {f2bf(v.x), f2bf(v.y), f2bf(v.z), f2bf(v.w)};
      *(uint2*)&xs[row][c4*4] = *(const uint2*)u4;
    }
    #pragma unroll
    for (int p = 0; p < 8; ++p) {          // stage WT 256o x 64f (uint4 = 8 shorts)
      const int idx = p*256 + t;
      const int o = idx >> 3, f8 = idx & 7;
      *(uint4*)&ws[o][f8*8] = *(const uint4*)(WT + (size_t)o*FI + f0 + f8*8);
    }
    __syncthreads();
    {                                      // s1,s2 partials: 16 f per thread
      const bf16x8 h0 = *(const bf16x8*)&xs[srow][fq];
      const bf16x8 h1 = *(const bf16x8*)&xs[srow][fq + 8];
      #pragma unroll
      for (int u = 0; u < 8; ++u) {
        const float hv0 = bf2f((unsigned short)h0[u]);
        const float hv1 = bf2f((unsigned short)h1[u]);
        sp1 = fmaf(hv0, was1[f0 + fq + u], sp1);
        sp1 = fmaf(hv1, was1[f0 + fq + 8 + u], sp1);
        sp2 = fmaf(hv0, was2[f0 + fq + u], sp2);
        sp2 = fmaf(hv1, was2[f0 + fq + 8 + u], sp2);
      }
    }
    #pragma unroll
    for (int ks = 0; ks < 2; ++ks) {
      bf16x8 af[4], bfr[4];
      #pragma unroll
      for (int mb = 0; mb < 4; ++mb)
        af[mb] = *(const bf16x8*)&xs[mb*16 + ln][ks*32 + q8];
      #pragma unroll
      for (int nb = 0; nb < 4; ++nb)
        bfr[nb] = *(const bf16x8*)&ws[wc + nb*16 + ln][ks*32 + q8];
      #pragma unroll
      for (int mb = 0; mb < 4; ++mb)
        #pragma unroll
        for (int nb = 0; nb < 4; ++nb)
          acc[mb][nb] = __builtin_amdgcn_mfma_f32_16x16x32_bf16(
              af[mb], bfr[nb], acc[mb][nb], 0, 0, 0);
    }
    __syncthreads();
  }
  sp1 += __shfl_xor(sp1, 1); sp2 += __shfl_xor(sp2, 1);
  sp1 += __shfl_xor(sp1, 2); sp2 += __shfl_xor(sp2, 2);
  if ((t & 3) == 0) {
    s1[b*NN + n0 + srow] = sp1;
    s2[b*NN + n0 + srow] = sp2;
  }
  const int quad = lane >> 4;
  #pragma unroll
  for (int mb = 0; mb < 4; ++mb)
    #pragma unroll
    for (int nb = 0; nb < 4; ++nb) {
      unsigned short u4[4];
      #pragma unroll
      for (int r = 0; r < 4; ++r) u4[r] = f2bf(acc[mb][nb][r]);
      const int o_loc = wc + nb*16 + ln;
      const int n_loc = mb*16 + quad*4;
      *(uint2*)(hbT + (size_t)(b*FO + o_loc)*NN + n0 + n_loc) = *(const uint2*)u4;
    }
}

// ---------------- K2: adj -> mask32 + column softmax partials (one pass) -----
__global__ __launch_bounds__(256) void adjstats_kernel(
    const int* __restrict__ adj, const float* __restrict__ s1, const float* __restrict__ s2,
    unsigned int* __restrict__ mask32, float* __restrict__ pm, float* __restrict__ pl) {
  const int t = threadIdx.x;
  const int jt = blockIdx.x, ic = blockIdx.y, b = blockIdx.z;
  const int i0 = ic*256;
  __shared__ unsigned short bitsm[16][260];   // [j16][i], pad 260 vs 256
  __shared__ float s1s[256];
  s1s[t] = s1[b*NN + i0 + t];
  const int rr = t >> 4, j16 = t & 15;
  #pragma unroll 4
  for (int p = 0; p < 16; ++p) {
    const int row = p*16 + rr;
    const int4* src = (const int4*)(adj + (size_t)(b*NN + i0 + row)*NN + jt*256 + j16*16);
    const int4 q0 = src[0], q1 = src[1], q2 = src[2], q3 = src[3];
    unsigned int m = 0;
    m |= (unsigned int)(q0.x != 0) << 0;  m |= (unsigned int)(q0.y != 0) << 1;
    m |= (unsigned int)(q0.z != 0) << 2;  m |= (unsigned int)(q0.w != 0) << 3;
    m |= (unsigned int)(q1.x != 0) << 4;  m |= (unsigned int)(q1.y != 0) << 5;
    m |= (unsigned int)(q1.z != 0) << 6;  m |= (unsigned int)(q1.w != 0) << 7;
    m |= (unsigned int)(q2.x != 0) << 8;  m |= (unsigned int)(q2.y != 0) << 9;
    m |= (unsigned int)(q2.z != 0) << 10; m |= (unsigned int)(q2.w != 0) << 11;
    m |= (unsigned int)(q3.x != 0) << 12; m |= (unsigned int)(q3.y != 0) << 13;
    m |= (unsigned int)(q3.z != 0) << 14; m |= (unsigned int)(q3.w != 0) << 15;
    bitsm[j16][row] = (unsigned short)m;
  }
  __syncthreads();
  #pragma unroll
  for (int p = 0; p < 8; ++p) {               // coalesced mask32 write
    const int idx = p*256 + t;
    const int il = idx >> 3, wl = idx & 7;
    const unsigned int d = (unsigned int)bitsm[2*wl][il]
                         | ((unsigned int)bitsm[2*wl + 1][il] << 16);
    mask32[(size_t)(b*NN + i0 + il)*64 + jt*8 + wl] = d;
  }
  const int j = jt*256 + t;
  const float s2j = s2[b*NN + j];
  const int c16 = t >> 4, sh = t & 15;
  float M0 = NEG_BIG, M1 = NEG_BIG, M2 = NEG_BIG, M3 = NEG_BIG;
  for (int i = 0; i < 256; i += 4) {
    const uint2 w = *(const uint2*)&bitsm[c16][i];
    M0 = fmaxf(M0, ((w.x >> sh) & 1u)        ? s1s[i+0] : NEG_BIG);
    M1 = fmaxf(M1, ((w.x >> (16+sh)) & 1u)   ? s1s[i+1] : NEG_BIG);
    M2 = fmaxf(M2, ((w.y >> sh) & 1u)        ? s1s[i+2] : NEG_BIG);
    M3 = fmaxf(M3, ((w.y >> (16+sh)) & 1u)   ? s1s[i+3] : NEG_BIG);
  }
  const float M = fmaxf(fmaxf(M0, M1), fmaxf(M2, M3));
  float m;
  if (M == NEG_BIG) m = NEG_BIG;
  else { const float e = M + s2j; m = fmaxf(e, ALPHA*e); }
  float l0 = 0.f, l1 = 0.f, l2 = 0.f, l3 = 0.f;
  for (int i = 0; i < 256; i += 4) {
    const uint2 w = *(const uint2*)&bitsm[c16][i];
    float e0 = s1s[i+0] + s2j; e0 = fmaxf(e0, ALPHA*e0);
    float e1 = s1s[i+1] + s2j; e1 = fmaxf(e1, ALPHA*e1);
    float e2 = s1s[i+2] + s2j; e2 = fmaxf(e2, ALPHA*e2);
    float e3 = s1s[i+3] + s2j; e3 = fmaxf(e3, ALPHA*e3);
    l0 += __expf((((w.x >> sh) & 1u)      ? e0 : NEG_BIG) - m);
    l1 += __expf((((w.x >> (16+sh)) & 1u) ? e1 : NEG_BIG) - m);
    l2 += __expf((((w.y >> sh) & 1u)      ? e2 : NEG_BIG) - m);
    l3 += __expf((((w.y >> (16+sh)) & 1u) ? e3 : NEG_BIG) - m);
  }
  pm[(ic*BATCH + b)*NN + j] = m;
  pl[(ic*BATCH + b)*NN + j] = (l0 + l1) + (l2 + l3);
}

// ---------------- K3: out = elu(P @ h). Tile 32i x 256o: P computed ONCE -----
// grid (it=64, b=8) = 512 blocks, 2/CU. Wave wv owns o-strip [wv*64, +64).
__global__ __launch_bounds__(256) void agg_kernel(
    const unsigned int* __restrict__ mask32, const float* __restrict__ s1,
    const float* __restrict__ s2, const float* __restrict__ pm, const float* __restrict__ pl,
    const unsigned short* __restrict__ hbT, float* __restrict__ out) {
  const int t = threadIdx.x;
  const int it = blockIdx.x, b = blockIdx.y;
  __shared__ __align__(16) unsigned short Pt[32*40];
  __shared__ __align__(16) unsigned short Vt[256*40];
  __shared__ float s2s[NN];
  __shared__ float mpls[NN];
  #pragma unroll
  for (int q = 0; q < 8; ++q) {               // combine: mpl = m + log l
    const int j = q*256 + t;
    float m = NEG_BIG;
    #pragma unroll
    for (int c = 0; c < 8; ++c) m = fmaxf(m, pm[(c*BATCH + b)*NN + j]);
    float l = 0.f;
    #pragma unroll
    for (int c = 0; c < 8; ++c)
      l += pl[(c*BATCH + b)*NN + j] * __expf(pm[(c*BATCH + b)*NN + j] - m);
    mpls[j] = m + __logf(l);
    s2s[j] = s2[b*NN + j];
  }
  const int prow = t >> 3;            // 0..31: P row
  const int kq = (t & 7) * 4;         // 4-k chunk within BK=32
  const int i = it*32 + prow;
  const float s1i = s1[b*NN + i];
  const unsigned int* m32row = mask32 + (size_t)(b*NN + i)*64;
  const int lane = t & 63, wv = t >> 6;
  const int wc = wv*64;
  const int ln = lane & 15, q8 = (lane >> 4)*8;
  floatx4 acc[2][4];
  #pragma unroll
  for (int mb = 0; mb < 2; ++mb)
    #pragma unroll
    for (int nb = 0; nb < 4; ++nb) acc[mb][nb] = (floatx4){0.f,0.f,0.f,0.f};
  __syncthreads();
  for (int kt = 0; kt < NN/32; ++kt) {
    const int j0 = kt*32;
    const unsigned int bits = m32row[kt] >> kq;
    __align__(8) unsigned short pv[4];
    #pragma unroll
    for (int kk = 0; kk < 4; ++kk) {
      const int k = j0 + kq + kk;
      float e = s1i + s2s[k];
      e = fmaxf(e, ALPHA*e);
      const float vvv = ((bits >> kk) & 1u) ? e : NEG_BIG;
      pv[kk] = f2bf(__expf(vvv - mpls[k]));
    }
    *(uint2*)&Pt[prow*40 + kq] = *(const uint2*)pv;
    #pragma unroll
    for (int p = 0; p < 4; ++p) {             // stage V: 256o x 32j
      const int idx = p*256 + t;
      const int row = idx >> 2, kc = (idx & 3)*8;
      *(uint4*)&Vt[row*40 + kc] =
          *(const uint4*)(hbT + (size_t)(b*FO + row)*NN + j0 + kc);
    }
    __syncthreads();
    bf16x8 af[2], bfr[4];
    #pragma unroll
    for (int mb = 0; mb < 2; ++mb)
      af[mb] = *(const bf16x8*)&Pt[(mb*16 + ln)*40 + q8];
    #pragma unroll
    for (int nb = 0; nb < 4; ++nb)
      bfr[nb] = *(const bf16x8*)&Vt[(wc + nb*16 + ln)*40 + q8];
    #pragma unroll
    for (int mb = 0; mb < 2; ++mb)
      #pragma unroll
      for (int nb = 0; nb < 4; ++nb)
        acc[mb][nb] = __builtin_amdgcn_mfma_f32_16x16x32_bf16(
            af[mb], bfr[nb], acc[mb][nb], 0, 0, 0);
    __syncthreads();
  }
  const int orow_base = it*32;
  #pragma unroll
  for (int mb = 0; mb < 2; ++mb)
    #pragma unroll
    for (int nb = 0; nb < 4; ++nb)
      #pragma unroll
      for (int r = 0; r < 4; ++r) {
        float vvv = acc[mb][nb][r];
        vvv = vvv > 0.f ? vvv : (__expf(vvv) - 1.f);
        const int m_loc = orow_base + mb*16 + (lane >> 4)*4 + r;
        const int n_loc = wc + nb*16 + ln;
        out[(size_t)(b*NN + m_loc)*FO + n_loc] = vvv;
      }
}

extern "C" void kernel_launch(void* const* d_in, const int* in_sizes, int n_in,
                              void* d_out, int out_size, void* d_ws, size_t ws_size,
                              hipStream_t stream) {
  const float* x  = (const float*)d_in[0];
  const int* adj  = (const int*)d_in[1];
  const float* W  = (const float*)d_in[2];
  const float* a  = (const float*)d_in[3];
  float* out = (float*)d_out;

  char* ws = (char*)d_ws;
  size_t off = 0;
  auto alloc = [&](size_t bytes) -> void* {
    void* p = ws + off; off += (bytes + 255) & ~(size_t)255; return p;
  };
  unsigned short* WT   = (unsigned short*)alloc((size_t)FI*FO*2);            // 128 KB
  float* wa1           = (float*)alloc(FO*4);
  float* wa2           = (float*)alloc(FO*4);
  unsigned short* hbT  = (unsigned short*)alloc((size_t)BATCH*FO*NN*2);      // 8 MB
  float* s1            = (float*)alloc((size_t)BATCH*NN*4);
  float* s2            = (float*)alloc((size_t)BATCH*NN*4);
  float* pm            = (float*)alloc((size_t)8*BATCH*NN*4);
  float* pl            = (float*)alloc((size_t)8*BATCH*NN*4);
  unsigned int* mask32 = (unsigned int*)alloc((size_t)BATCH*NN*(NN/32)*4);   // 4 MB

  prep_kernel<<<dim3(72), dim3(256), 0, stream>>>(W, a, WT, wa1, wa2);
  hgemm_kernel<<<dim3(32, BATCH), dim3(256), 0, stream>>>(x, WT, wa1, wa2, hbT, s1, s2);
  adjstats_kernel<<<dim3(8, 8, BATCH), dim3(256), 0, stream>>>(adj, s1, s2, mask32, pm, pl);
  agg_kernel<<<dim3(64, BATCH), dim3(256), 0, stream>>>(mask32, s1, s2, pm, pl, hbT, out);
}

// Round 8
// 290.147 us; speedup vs baseline: 1.0164x; 1.0122x over previous
//
#include <hip/hip_runtime.h>
#include <hip/hip_bf16.h>

#define BATCH 8
#define NN 2048
#define FI 256
#define FO 256
#define ALPHA 0.2f
#define NEG_BIG -9000000000000000.0f

typedef short bf16x8 __attribute__((ext_vector_type(8)));
typedef float floatx4 __attribute__((ext_vector_type(4)));

static __device__ __forceinline__ unsigned short f2bf(float f) {
  return __builtin_bit_cast(unsigned short, __float2bfloat16(f));
}
static __device__ __forceinline__ float bf2f(unsigned short u) {
  unsigned int x = ((unsigned int)u) << 16;
  return __builtin_bit_cast(float, x);
}

// ---------------- K0: prep — WT (bf16, [o][f]) + wa1/wa2 = W@a halves -------
__global__ __launch_bounds__(256) void prep_kernel(
    const float* __restrict__ W, const float* __restrict__ a,
    unsigned short* __restrict__ WT, float* __restrict__ wa1, float* __restrict__ wa2) {
  const int t = threadIdx.x;
  const int blk = blockIdx.x;
  if (blk < 64) {
    __shared__ float xt[32][33];
    const int tr = blk >> 3, tc = blk & 7;        // f-tile, o-tile
    const int r = t >> 3, o4 = t & 7;
    const float4 v = *(const float4*)(W + (size_t)(tr*32 + r)*FO + tc*32 + o4*4);
    xt[o4*4+0][r] = v.x; xt[o4*4+1][r] = v.y; xt[o4*4+2][r] = v.z; xt[o4*4+3][r] = v.w;
    __syncthreads();
    const int ol = t >> 3, f4 = t & 7;
    unsigned short u4[4];
    #pragma unroll
    for (int u = 0; u < 4; ++u) u4[u] = f2bf(xt[ol][f4*4 + u]);
    *(uint2*)(WT + (size_t)(tc*32 + ol)*FI + tr*32 + f4*4) = *(const uint2*)u4;
  } else {
    const int bk = blk - 64;
    const int f = bk*32 + (t >> 3), oc = t & 7;
    const float4* wrow = (const float4*)(W + (size_t)f*FO) + oc*8;
    const float4* a1v  = (const float4*)a + oc*8;
    const float4* a2v  = (const float4*)(a + FO) + oc*8;
    float p1 = 0.f, p2 = 0.f;
    #pragma unroll
    for (int i = 0; i < 8; ++i) {
      const float4 w = wrow[i], b1 = a1v[i], b2 = a2v[i];
      p1 += w.x*b1.x + w.y*b1.y + w.z*b1.z + w.w*b1.w;
      p2 += w.x*b2.x + w.y*b2.y + w.z*b2.z + w.w*b2.w;
    }
    p1 += __shfl_xor(p1, 1); p2 += __shfl_xor(p2, 1);
    p1 += __shfl_xor(p1, 2); p2 += __shfl_xor(p2, 2);
    p1 += __shfl_xor(p1, 4); p2 += __shfl_xor(p2, 4);
    if (oc == 0) { wa1[f] = p1; wa2[f] = p2; }
  }
}

// ---------------- K1: hT = (x@W)^T via bf16 MFMA, fused s1+s2 ---------------
// grid (nt=64, b=8) = 512 blocks -> 2 blocks/CU. Tile 32n x 256o, BK=64.
__global__ __launch_bounds__(256) void hgemm_kernel(
    const float* __restrict__ x, const unsigned short* __restrict__ WT,
    const float* __restrict__ wa1, const float* __restrict__ wa2,
    unsigned short* __restrict__ hbT, float* __restrict__ s1, float* __restrict__ s2) {
  const int t = threadIdx.x;
  const int nt = blockIdx.x, b = blockIdx.y;
  const int n0 = nt*32;
  __shared__ __align__(16) unsigned short xs[32][72];
  __shared__ __align__(16) unsigned short ws[256][72];
  __shared__ float was1[256], was2[256];
  was1[t] = wa1[t];
  was2[t] = wa2[t];
  const int lane = t & 63, wv = t >> 6;
  const int wc = wv*64;
  const int ln = lane & 15, q8 = (lane >> 4)*8;
  const int srow = t >> 3, fq = (t & 7)*8;      // 8 threads/row, 8 f each
  floatx4 acc[2][4];
  #pragma unroll
  for (int mb = 0; mb < 2; ++mb)
    #pragma unroll
    for (int nb = 0; nb < 4; ++nb) acc[mb][nb] = (floatx4){0.f,0.f,0.f,0.f};
  float sp1 = 0.f, sp2 = 0.f;
  for (int kt = 0; kt < 4; ++kt) {
    const int f0 = kt*64;
    #pragma unroll
    for (int p = 0; p < 2; ++p) {          // stage x 32n x 64f fp32 -> bf16
      const int idx = p*256 + t;
      const int row = idx >> 4, c4 = idx & 15;
      const float4 v = *(const float4*)(x + (size_t)(b*NN + n0 + row)*FI + f0 + c4*4);
      unsigned short u4[4] = {f2bf(v.x), f2bf(v.y), f2bf(v.z), f2bf(v.w)};
      *(uint2*)&xs[row][c4*4] = *(const uint2*)u4;
    }
    #pragma unroll
    for (int p = 0; p < 8; ++p) {          // stage WT 256o x 64f
      const int idx = p*256 + t;
      const int o = idx >> 3, f8 = idx & 7;
      *(uint4*)&ws[o][f8*8] = *(const uint4*)(WT + (size_t)o*FI + f0 + f8*8);
    }
    __syncthreads();
    {                                      // s1,s2 partials: 8 f per thread
      const bf16x8 h0 = *(const bf16x8*)&xs[srow][fq];
      #pragma unroll
      for (int u = 0; u < 8; ++u) {
        const float hv = bf2f((unsigned short)h0[u]);
        sp1 = fmaf(hv, was1[f0 + fq + u], sp1);
        sp2 = fmaf(hv, was2[f0 + fq + u], sp2);
      }
    }
    #pragma unroll
    for (int ks = 0; ks < 2; ++ks) {
      bf16x8 af[2], bfr[4];
      #pragma unroll
      for (int mb = 0; mb < 2; ++mb)
        af[mb] = *(const bf16x8*)&xs[mb*16 + ln][ks*32 + q8];
      #pragma unroll
      for (int nb = 0; nb < 4; ++nb)
        bfr[nb] = *(const bf16x8*)&ws[wc + nb*16 + ln][ks*32 + q8];
      #pragma unroll
      for (int mb = 0; mb < 2; ++mb)
        #pragma unroll
        for (int nb = 0; nb < 4; ++nb)
          acc[mb][nb] = __builtin_amdgcn_mfma_f32_16x16x32_bf16(
              af[mb], bfr[nb], acc[mb][nb], 0, 0, 0);
    }
    __syncthreads();
  }
  sp1 += __shfl_xor(sp1, 1); sp2 += __shfl_xor(sp2, 1);
  sp1 += __shfl_xor(sp1, 2); sp2 += __shfl_xor(sp2, 2);
  sp1 += __shfl_xor(sp1, 4); sp2 += __shfl_xor(sp2, 4);
  if ((t & 7) == 0) {
    s1[b*NN + n0 + srow] = sp1;
    s2[b*NN + n0 + srow] = sp2;
  }
  const int quad = lane >> 4;
  #pragma unroll
  for (int mb = 0; mb < 2; ++mb)
    #pragma unroll
    for (int nb = 0; nb < 4; ++nb) {
      unsigned short u4[4];
      #pragma unroll
      for (int r = 0; r < 4; ++r) u4[r] = f2bf(acc[mb][nb][r]);
      const int o_loc = wc + nb*16 + ln;
      const int n_loc = mb*16 + quad*4;
      *(uint2*)(hbT + (size_t)(b*FO + o_loc)*NN + n0 + n_loc) = *(const uint2*)u4;
    }
}

// ---------------- K2: adj -> mask32 + column softmax partials (one pass) -----
__global__ __launch_bounds__(256) void adjstats_kernel(
    const int* __restrict__ adj, const float* __restrict__ s1, const float* __restrict__ s2,
    unsigned int* __restrict__ mask32, float* __restrict__ pm, float* __restrict__ pl) {
  const int t = threadIdx.x;
  const int jt = blockIdx.x, ic = blockIdx.y, b = blockIdx.z;
  const int i0 = ic*256;
  __shared__ unsigned short bitsm[16][260];   // [j16][i], pad 260 vs 256
  __shared__ float s1s[256];
  s1s[t] = s1[b*NN + i0 + t];
  const int rr = t >> 4, j16 = t & 15;
  #pragma unroll 4
  for (int p = 0; p < 16; ++p) {
    const int row = p*16 + rr;
    const int4* src = (const int4*)(adj + (size_t)(b*NN + i0 + row)*NN + jt*256 + j16*16);
    const int4 q0 = src[0], q1 = src[1], q2 = src[2], q3 = src[3];
    unsigned int m = 0;
    m |= (unsigned int)(q0.x != 0) << 0;  m |= (unsigned int)(q0.y != 0) << 1;
    m |= (unsigned int)(q0.z != 0) << 2;  m |= (unsigned int)(q0.w != 0) << 3;
    m |= (unsigned int)(q1.x != 0) << 4;  m |= (unsigned int)(q1.y != 0) << 5;
    m |= (unsigned int)(q1.z != 0) << 6;  m |= (unsigned int)(q1.w != 0) << 7;
    m |= (unsigned int)(q2.x != 0) << 8;  m |= (unsigned int)(q2.y != 0) << 9;
    m |= (unsigned int)(q2.z != 0) << 10; m |= (unsigned int)(q2.w != 0) << 11;
    m |= (unsigned int)(q3.x != 0) << 12; m |= (unsigned int)(q3.y != 0) << 13;
    m |= (unsigned int)(q3.z != 0) << 14; m |= (unsigned int)(q3.w != 0) << 15;
    bitsm[j16][row] = (unsigned short)m;
  }
  __syncthreads();
  #pragma unroll
  for (int p = 0; p < 8; ++p) {               // coalesced mask32 write
    const int idx = p*256 + t;
    const int il = idx >> 3, wl = idx & 7;
    const unsigned int d = (unsigned int)bitsm[2*wl][il]
                         | ((unsigned int)bitsm[2*wl + 1][il] << 16);
    mask32[(size_t)(b*NN + i0 + il)*64 + jt*8 + wl] = d;
  }
  const int j = jt*256 + t;
  const float s2j = s2[b*NN + j];
  const int c16 = t >> 4, sh = t & 15;
  float M0 = NEG_BIG, M1 = NEG_BIG, M2 = NEG_BIG, M3 = NEG_BIG;
  for (int i = 0; i < 256; i += 4) {
    const uint2 w = *(const uint2*)&bitsm[c16][i];
    M0 = fmaxf(M0, ((w.x >> sh) & 1u)        ? s1s[i+0] : NEG_BIG);
    M1 = fmaxf(M1, ((w.x >> (16+sh)) & 1u)   ? s1s[i+1] : NEG_BIG);
    M2 = fmaxf(M2, ((w.y >> sh) & 1u)        ? s1s[i+2] : NEG_BIG);
    M3 = fmaxf(M3, ((w.y >> (16+sh)) & 1u)   ? s1s[i+3] : NEG_BIG);
  }
  const float M = fmaxf(fmaxf(M0, M1), fmaxf(M2, M3));
  float m;
  if (M == NEG_BIG) m = NEG_BIG;
  else { const float e = M + s2j; m = fmaxf(e, ALPHA*e); }
  float l0 = 0.f, l1 = 0.f, l2 = 0.f, l3 = 0.f;
  for (int i = 0; i < 256; i += 4) {
    const uint2 w = *(const uint2*)&bitsm[c16][i];
    float e0 = s1s[i+0] + s2j; e0 = fmaxf(e0, ALPHA*e0);
    float e1 = s1s[i+1] + s2j; e1 = fmaxf(e1, ALPHA*e1);
    float e2 = s1s[i+2] + s2j; e2 = fmaxf(e2, ALPHA*e2);
    float e3 = s1s[i+3] + s2j; e3 = fmaxf(e3, ALPHA*e3);
    l0 += __expf((((w.x >> sh) & 1u)      ? e0 : NEG_BIG) - m);
    l1 += __expf((((w.x >> (16+sh)) & 1u) ? e1 : NEG_BIG) - m);
    l2 += __expf((((w.y >> sh) & 1u)      ? e2 : NEG_BIG) - m);
    l3 += __expf((((w.y >> (16+sh)) & 1u) ? e3 : NEG_BIG) - m);
  }
  pm[(ic*BATCH + b)*NN + j] = m;
  pl[(ic*BATCH + b)*NN + j] = (l0 + l1) + (l2 + l3);
}

// ---------------- K3: out = elu(P @ h). Tile 32i x 256o, BK=64 --------------
// grid (it=64, b=8) = 512 blocks, 2/CU. 64 barriers instead of 128.
__global__ __launch_bounds__(256) void agg_kernel(
    const unsigned int* __restrict__ mask32, const float* __restrict__ s1,
    const float* __restrict__ s2, const float* __restrict__ pm, const float* __restrict__ pl,
    const unsigned short* __restrict__ hbT, float* __restrict__ out) {
  const int t = threadIdx.x;
  const int it = blockIdx.x, b = blockIdx.y;
  __shared__ __align__(16) unsigned short Pt[32*72];
  __shared__ __align__(16) unsigned short Vt[256*72];
  __shared__ float s2s[NN];
  __shared__ float mpls[NN];
  #pragma unroll
  for (int q = 0; q < 8; ++q) {               // combine: mpl = m + log l
    const int j = q*256 + t;
    float m = NEG_BIG;
    #pragma unroll
    for (int c = 0; c < 8; ++c) m = fmaxf(m, pm[(c*BATCH + b)*NN + j]);
    float l = 0.f;
    #pragma unroll
    for (int c = 0; c < 8; ++c)
      l += pl[(c*BATCH + b)*NN + j] * __expf(pm[(c*BATCH + b)*NN + j] - m);
    mpls[j] = m + __logf(l);
    s2s[j] = s2[b*NN + j];
  }
  const int prow = t >> 3;            // 0..31: P row
  const int kq8 = (t & 7) * 8;        // 8-k chunk within BK=64
  const int i = it*32 + prow;
  const float s1i = s1[b*NN + i];
  const unsigned int* m32row = mask32 + (size_t)(b*NN + i)*64;
  const int lane = t & 63, wv = t >> 6;
  const int wc = wv*64;
  const int ln = lane & 15, q8 = (lane >> 4)*8;
  floatx4 acc[2][4];
  #pragma unroll
  for (int mb = 0; mb < 2; ++mb)
    #pragma unroll
    for (int nb = 0; nb < 4; ++nb) acc[mb][nb] = (floatx4){0.f,0.f,0.f,0.f};
  __syncthreads();
  for (int kt = 0; kt < NN/64; ++kt) {
    const int j0 = kt*64;
    const unsigned int bits = m32row[kt*2 + (kq8 >> 5)] >> (kq8 & 31);
    __align__(16) unsigned short pv[8];
    #pragma unroll
    for (int kk = 0; kk < 8; ++kk) {
      const int k = j0 + kq8 + kk;
      float e = s1i + s2s[k];
      e = fmaxf(e, ALPHA*e);
      const float vvv = ((bits >> kk) & 1u) ? e : NEG_BIG;
      pv[kk] = f2bf(__expf(vvv - mpls[k]));
    }
    *(uint4*)&Pt[prow*72 + kq8] = *(const uint4*)pv;
    #pragma unroll
    for (int p = 0; p < 8; ++p) {             // stage V: 256o x 64j
      const int idx = p*256 + t;
      const int row = idx >> 3, kc = (idx & 7)*8;
      *(uint4*)&Vt[row*72 + kc] =
          *(const uint4*)(hbT + (size_t)(b*FO + row)*NN + j0 + kc);
    }
    __syncthreads();
    #pragma unroll
    for (int ks = 0; ks < 2; ++ks) {
      bf16x8 af[2], bfr[4];
      #pragma unroll
      for (int mb = 0; mb < 2; ++mb)
        af[mb] = *(const bf16x8*)&Pt[(mb*16 + ln)*72 + ks*32 + q8];
      #pragma unroll
      for (int nb = 0; nb < 4; ++nb)
        bfr[nb] = *(const bf16x8*)&Vt[(wc + nb*16 + ln)*72 + ks*32 + q8];
      #pragma unroll
      for (int mb = 0; mb < 2; ++mb)
        #pragma unroll
        for (int nb = 0; nb < 4; ++nb)
          acc[mb][nb] = __builtin_amdgcn_mfma_f32_16x16x32_bf16(
              af[mb], bfr[nb], acc[mb][nb], 0, 0, 0);
    }
    __syncthreads();
  }
  const int orow_base = it*32;
  #pragma unroll
  for (int mb = 0; mb < 2; ++mb)
    #pragma unroll
    for (int nb = 0; nb < 4; ++nb)
      #pragma unroll
      for (int r = 0; r < 4; ++r) {
        float vvv = acc[mb][nb][r];
        vvv = vvv > 0.f ? vvv : (__expf(vvv) - 1.f);
        const int m_loc = orow_base + mb*16 + (lane >> 4)*4 + r;
        const int n_loc = wc + nb*16 + ln;
        out[(size_t)(b*NN + m_loc)*FO + n_loc] = vvv;
      }
}

extern "C" void kernel_launch(void* const* d_in, const int* in_sizes, int n_in,
                              void* d_out, int out_size, void* d_ws, size_t ws_size,
                              hipStream_t stream) {
  const float* x  = (const float*)d_in[0];
  const int* adj  = (const int*)d_in[1];
  const float* W  = (const float*)d_in[2];
  const float* a  = (const float*)d_in[3];
  float* out = (float*)d_out;

  char* ws = (char*)d_ws;
  size_t off = 0;
  auto alloc = [&](size_t bytes) -> void* {
    void* p = ws + off; off += (bytes + 255) & ~(size_t)255; return p;
  };
  unsigned short* WT   = (unsigned short*)alloc((size_t)FI*FO*2);            // 128 KB
  float* wa1           = (float*)alloc(FO*4);
  float* wa2           = (float*)alloc(FO*4);
  unsigned short* hbT  = (unsigned short*)alloc((size_t)BATCH*FO*NN*2);      // 8 MB
  float* s1            = (float*)alloc((size_t)BATCH*NN*4);
  float* s2            = (float*)alloc((size_t)BATCH*NN*4);
  float* pm            = (float*)alloc((size_t)8*BATCH*NN*4);
  float* pl            = (float*)alloc((size_t)8*BATCH*NN*4);
  unsigned int* mask32 = (unsigned int*)alloc((size_t)BATCH*NN*(NN/32)*4);   // 4 MB

  prep_kernel<<<dim3(72), dim3(256), 0, stream>>>(W, a, WT, wa1, wa2);
  hgemm_kernel<<<dim3(64, BATCH), dim3(256), 0, stream>>>(x, WT, wa1, wa2, hbT, s1, s2);
  adjstats_kernel<<<dim3(8, 8, BATCH), dim3(256), 0, stream>>>(adj, s1, s2, mask32, pm, pl);
  agg_kernel<<<dim3(64, BATCH), dim3(256), 0, stream>>>(mask32, s1, s2, pm, pl, hbT, out);
}